// Round 6
// baseline (215.194 us; speedup 1.0000x reference)
//
#include <hip/hip_runtime.h>
#include <stdint.h>
#include <stddef.h>

typedef unsigned short u16;
typedef __attribute__((ext_vector_type(8))) short s16x8;    // bf16 MFMA A/B frag (4 VGPR)
typedef __attribute__((ext_vector_type(8))) unsigned short u16x8;
typedef __attribute__((ext_vector_type(4))) unsigned short u16x4;
typedef __attribute__((ext_vector_type(4))) float f32x4;

typedef __attribute__((address_space(3))) void* as3_void_p;
typedef const __attribute__((address_space(1))) void* as1_cvoid_p;

#define GLD16(gp, lp) __builtin_amdgcn_global_load_lds((as1_cvoid_p)(gp), (as3_void_p)(lp), 16, 0, 0)

enum {
  NS = 2048, NF = 512, NH = 512, NW = 5,
  NROW = 32768,            // B*S
  K2 = NW * NF             // 2560
};

__device__ __forceinline__ u16 f2bf(float f) {
  unsigned u = __float_as_uint(f);
  u += 0x7FFFu + ((u >> 16) & 1u);     // round-to-nearest-even
  return (u16)(u >> 16);
}
__device__ __forceinline__ float bf2f(u16 v) {
  return __uint_as_float(((unsigned)v) << 16);
}

// ---------------- conversion kernels ----------------

__global__ __launch_bounds__(256) void cvtX(const float* __restrict__ X, u16* __restrict__ Xb) {
  int i = blockIdx.x * 256 + threadIdx.x;          // 0 .. NROW*NF/4
  f32x4 v = ((const f32x4*)X)[i];
  u16x4 o;
  o.x = f2bf(v.x); o.y = f2bf(v.y); o.z = f2bf(v.z); o.w = f2bf(v.w);
  ((u16x4*)Xb)[i] = o;
}

// Wt1[j][f]: j<512 -> Wq[:,j]; else Wk[:,j-512].  Wt2[h][k] = cnn_W[k][h], k = w*512+f.
__global__ __launch_bounds__(256) void cvtW(const float* __restrict__ Wq, const float* __restrict__ Wk,
                                            const float* __restrict__ cnnW,
                                            u16* __restrict__ Wt1, u16* __restrict__ Wt2) {
  int i = blockIdx.x * 256 + threadIdx.x;          // 0 .. 1024*512 + 512*2560
  if (i < 1024 * 512) {
    int j = i >> 9, f = i & 511;
    float v = (j < 512) ? Wq[(size_t)f * 512 + j] : Wk[(size_t)f * 512 + (j - 512)];
    Wt1[i] = f2bf(v);
  } else {
    int t = i - 1024 * 512;                        // < 512*2560
    int h = t / K2, k = t % K2;
    Wt2[t] = f2bf(cnnW[(size_t)k * 512 + h]);
  }
}

// ---------------- GEMM1: QKb[n][0:1024] = Xb @ Wt1^T  (bf16 out) ----------------
// 128x128 block tile, 8 waves (2x4, wave tile 64x32), BK=64, double-buffered LDS:
// STAGE(next kt) issued BEFORE compute(cur) -> load latency hides under MFMA; one
// barrier per K-step (compiler's vmcnt(0)-at-barrier is the intended wait).
// T2 XOR-swizzle via pre-swizzled global source (rule #21).

__global__ __launch_bounds__(512, 4) void gemm_qk(const u16* __restrict__ Xb,
                                                  const u16* __restrict__ Wt1,
                                                  u16* __restrict__ QKb) {
  __shared__ u16 As[2][128 * 64];                  // 2 x 16 KB
  __shared__ u16 Bs[2][128 * 64];                  // 2 x 16 KB
  const int tid  = threadIdx.x;
  const int lane = tid & 63, wid = tid >> 6;
  const int wr = wid >> 2, wc = wid & 3;           // 2 x 4 wave grid
  const int fr = lane & 15, fq = lane >> 4;
  // XCD-chunk swizzle: 2048 blocks, one XCD keeps contiguous row-panels
  const int wgid = (blockIdx.x & 7) * 256 + (blockIdx.x >> 3);
  const int brow = (wgid >> 3) * 128;
  const int bcol = (wgid & 7) * 128;

  // tid-static staging geometry (4 x GLD16 per thread per K-step)
  const int rsub = tid >> 3;                                   // 0..63
  const int cb   = (((tid & 7) ^ (rsub & 7)) << 4);            // swizzled source column byte
  const char* gA0 = (const char*)(Xb  + (size_t)(brow + rsub) * NF) + cb;
  const char* gA1 = (const char*)(Xb  + (size_t)(brow + 64 + rsub) * NF) + cb;
  const char* gB0 = (const char*)(Wt1 + (size_t)(bcol + rsub) * NF) + cb;
  const char* gB1 = (const char*)(Wt1 + (size_t)(bcol + 64 + rsub) * NF) + cb;

  f32x4 acc[4][2] = {};

  // prologue: stage kt=0 into buf 0
  GLD16(gA0, (char*)As[0] + tid * 16);
  GLD16(gA1, (char*)As[0] + 8192 + tid * 16);
  GLD16(gB0, (char*)Bs[0] + tid * 16);
  GLD16(gB1, (char*)Bs[0] + 8192 + tid * 16);
  __syncthreads();

  int cur = 0;
  for (int kt = 0; kt < 8; ++kt) {
    if (kt + 1 < 8) {                              // stage next K-step into other buffer
      int o = (kt + 1) * 128;
      GLD16(gA0 + o, (char*)As[cur ^ 1] + tid * 16);
      GLD16(gA1 + o, (char*)As[cur ^ 1] + 8192 + tid * 16);
      GLD16(gB0 + o, (char*)Bs[cur ^ 1] + tid * 16);
      GLD16(gB1 + o, (char*)Bs[cur ^ 1] + 8192 + tid * 16);
    }
    const char* Ab = (const char*)As[cur];
    const char* Bb = (const char*)Bs[cur];
#pragma unroll
    for (int kk = 0; kk < 2; ++kk) {
      s16x8 af[4], bfr[2];
#pragma unroll
      for (int m = 0; m < 4; ++m) {
        int row = wr * 64 + m * 16 + fr;
        af[m] = *(const s16x8*)(Ab + row * 128 + ((kk * 64 + fq * 16) ^ ((row & 7) << 4)));
      }
#pragma unroll
      for (int n = 0; n < 2; ++n) {
        int row = wc * 32 + n * 16 + fr;
        bfr[n] = *(const s16x8*)(Bb + row * 128 + ((kk * 64 + fq * 16) ^ ((row & 7) << 4)));
      }
#pragma unroll
      for (int m = 0; m < 4; ++m)
#pragma unroll
        for (int n = 0; n < 2; ++n)
          acc[m][n] = __builtin_amdgcn_mfma_f32_16x16x32_bf16(af[m], bfr[n], acc[m][n], 0, 0, 0);
    }
    __syncthreads();                               // drains next-stage loads + LDS reads done
    cur ^= 1;
  }

#pragma unroll
  for (int m = 0; m < 4; ++m)
#pragma unroll
    for (int n = 0; n < 2; ++n)
#pragma unroll
      for (int r = 0; r < 4; ++r) {
        int row = brow + wr * 64 + m * 16 + fq * 4 + r;
        int col = bcol + wc * 32 + n * 16 + fr;
        QKb[(size_t)row * 1024 + col] = f2bf(acc[m][n][r]);
      }
}

// ---------------- scores + softmax -> att[n][5] ----------------

__global__ __launch_bounds__(256) void scores_att(const u16* __restrict__ QKb,
                                                  const float* __restrict__ vatt,
                                                  float* __restrict__ att) {
  const int lane = threadIdx.x & 63;
  const int wid  = threadIdx.x >> 6;
  const int n = blockIdx.x * 4 + wid;
  const int s = n & (NS - 1);
  const int h0 = lane * 8;

  u16x8 qv = *(const u16x8*)(QKb + (size_t)n * 1024 + h0);
  f32x4 va0 = *(const f32x4*)(vatt + h0);
  f32x4 va1 = *(const f32x4*)(vatt + h0 + 4);
  float q[8], vv[8];
#pragma unroll
  for (int j = 0; j < 8; ++j) q[j] = bf2f(qv[j]);
  vv[0] = va0.x; vv[1] = va0.y; vv[2] = va0.z; vv[3] = va0.w;
  vv[4] = va1.x; vv[5] = va1.y; vv[6] = va1.z; vv[7] = va1.w;

  float sc[5];
#pragma unroll
  for (int w = 0; w < 5; ++w) {
    int sp = s + w - 2;
    u16x8 kv = {0, 0, 0, 0, 0, 0, 0, 0};
    if (sp >= 0 && sp < NS)
      kv = *(const u16x8*)(QKb + (size_t)(n + w - 2) * 1024 + 512 + h0);
    float acc = 0.f;
#pragma unroll
    for (int j = 0; j < 8; ++j) {
      float x = q[j] + bf2f(kv[j]);
      x = fminf(fmaxf(x, -15.f), 15.f);
      float e = __expf(2.f * x);
      acc += vv[j] * ((e - 1.f) / (e + 1.f));     // tanh(x)
    }
    sc[w] = acc;
  }
#pragma unroll
  for (int w = 0; w < 5; ++w)
#pragma unroll
    for (int o = 32; o > 0; o >>= 1)
      sc[w] += __shfl_xor(sc[w], o, 64);

  if (lane == 0) {
    float m = sc[0];
#pragma unroll
    for (int w = 1; w < 5; ++w) m = fmaxf(m, sc[w]);
    float e[5], sum = 0.f;
#pragma unroll
    for (int w = 0; w < 5; ++w) { e[w] = __expf(sc[w] - m); sum += e[w]; }
    float inv = 1.f / sum;
#pragma unroll
    for (int w = 0; w < 5; ++w) att[(size_t)n * 5 + w] = e[w] * inv;
  }
}

// ---------------- GEMM2 (fold epilogue): out[n][h] = b[h] + sum_w att[n][w]*(X[n+w-2]@W_w)[h] ----
// 128x128 block tile, 8 waves (2x4, wave tile 64x32), double-buffered LDS with
// STAGE-before-compute (depth-1 pipeline). Per w: A = unscaled shifted Xb rows; after
// each w's K-range, fold acc into accOut with att[n][w] (OOB rows weight 0, rows clamped).

__global__ __launch_bounds__(512, 4) void gemm_out(const u16* __restrict__ Xb,
                                                   const u16* __restrict__ Wt2,
                                                   const float* __restrict__ att,
                                                   const float* __restrict__ cnnb,
                                                   float* __restrict__ out) {
  __shared__ u16 As[2][128 * 64];                  // 2 x 16 KB
  __shared__ u16 Bs[2][128 * 64];                  // 2 x 16 KB
  __shared__ float att_s[128 * 5];
  const int tid  = threadIdx.x;
  const int lane = tid & 63, wid = tid >> 6;
  const int wr = wid >> 2, wc = wid & 3;           // 2 x 4 wave grid, wave tile 64x32
  const int fr = lane & 15, fq = lane >> 4;
  // XCD-chunk swizzle: 1024 blocks, contiguous row-panels per XCD (col-fast within)
  const int wgid = (blockIdx.x & 7) * 128 + (blockIdx.x >> 3);
  const int brow = (wgid >> 2) * 128;
  const int bcol = (wgid & 3) * 128;

  if (tid < 128) {
    int s = (brow + tid) & (NS - 1);
#pragma unroll
    for (int w = 0; w < 5; ++w) {
      int sp = s + w - 2;
      att_s[tid * 5 + w] = (sp >= 0 && sp < NS) ? att[(size_t)(brow + tid) * 5 + w] : 0.f;
    }
  }

  // tid-static staging geometry
  const int rsub = tid >> 3;                                   // 0..63
  const int cb   = (((tid & 7) ^ (rsub & 7)) << 4);            // swizzled source column byte
  const char* gB0 = (const char*)(Wt2 + (size_t)(bcol + rsub) * K2) + cb;
  const char* gB1 = (const char*)(Wt2 + (size_t)(bcol + 64 + rsub) * K2) + cb;

  // stage iteration `it` (= w*8+kt) into buffer `buf`
  auto stage = [&](int buf, int it) {
    int wn = it >> 3, ktn = it & 7;
    int g0 = brow + rsub + wn - 2;
    int g1 = brow + 64 + rsub + wn - 2;
    g0 = g0 < 0 ? 0 : (g0 >= NROW ? NROW - 1 : g0);   // clamp; fold weight 0 for invalid rows
    g1 = g1 < 0 ? 0 : (g1 >= NROW ? NROW - 1 : g1);
    int ko = ktn * 128;
    GLD16((const char*)(Xb + (size_t)g0 * NF) + cb + ko, (char*)As[buf] + tid * 16);
    GLD16((const char*)(Xb + (size_t)g1 * NF) + cb + ko, (char*)As[buf] + 8192 + tid * 16);
    GLD16(gB0 + wn * 1024 + ko, (char*)Bs[buf] + tid * 16);
    GLD16(gB1 + wn * 1024 + ko, (char*)Bs[buf] + 8192 + tid * 16);
  };

  f32x4 acc[4][2] = {};
  f32x4 accOut[4][2] = {};

  stage(0, 0);
  __syncthreads();                                 // also covers att_s writes

  int cur = 0;
  for (int it = 0; it < 40; ++it) {
    if (it + 1 < 40) stage(cur ^ 1, it + 1);
    const char* Ab = (const char*)As[cur];
    const char* Bb = (const char*)Bs[cur];
#pragma unroll
    for (int kk = 0; kk < 2; ++kk) {
      s16x8 af[4], bfr[2];
#pragma unroll
      for (int m = 0; m < 4; ++m) {
        int row = wr * 64 + m * 16 + fr;
        af[m] = *(const s16x8*)(Ab + row * 128 + ((kk * 64 + fq * 16) ^ ((row & 7) << 4)));
      }
#pragma unroll
      for (int n = 0; n < 2; ++n) {
        int row = wc * 32 + n * 16 + fr;
        bfr[n] = *(const s16x8*)(Bb + row * 128 + ((kk * 64 + fq * 16) ^ ((row & 7) << 4)));
      }
#pragma unroll
      for (int m = 0; m < 4; ++m)
#pragma unroll
        for (int n = 0; n < 2; ++n)
          acc[m][n] = __builtin_amdgcn_mfma_f32_16x16x32_bf16(af[m], bfr[n], acc[m][n], 0, 0, 0);
    }
    if ((it & 7) == 7) {
      // fold: accOut += att[row][w] * acc; acc = 0  (registers + att_s only)
      int w = it >> 3;
#pragma unroll
      for (int m = 0; m < 4; ++m) {
        float a0 = att_s[(wr * 64 + m * 16 + fq * 4 + 0) * 5 + w];
        float a1 = att_s[(wr * 64 + m * 16 + fq * 4 + 1) * 5 + w];
        float a2 = att_s[(wr * 64 + m * 16 + fq * 4 + 2) * 5 + w];
        float a3 = att_s[(wr * 64 + m * 16 + fq * 4 + 3) * 5 + w];
#pragma unroll
        for (int n = 0; n < 2; ++n) {
          accOut[m][n][0] += a0 * acc[m][n][0];
          accOut[m][n][1] += a1 * acc[m][n][1];
          accOut[m][n][2] += a2 * acc[m][n][2];
          accOut[m][n][3] += a3 * acc[m][n][3];
          acc[m][n] = f32x4{0.f, 0.f, 0.f, 0.f};
        }
      }
    }
    __syncthreads();                               // drains next-stage loads + LDS reads done
    cur ^= 1;
  }

#pragma unroll
  for (int m = 0; m < 4; ++m)
#pragma unroll
    for (int n = 0; n < 2; ++n)
#pragma unroll
      for (int r = 0; r < 4; ++r) {
        int row = brow + wr * 64 + m * 16 + fq * 4 + r;
        int col = bcol + wc * 32 + n * 16 + fr;
        out[(size_t)row * NH + col] = accOut[m][n][r] + cnnb[col];
      }
}

// ---------------- launch ----------------

extern "C" void kernel_launch(void* const* d_in, const int* in_sizes, int n_in,
                              void* d_out, int out_size, void* d_ws, size_t ws_size,
                              hipStream_t stream) {
  const float* X    = (const float*)d_in[0];
  const float* Wq   = (const float*)d_in[1];
  const float* Wk   = (const float*)d_in[2];
  const float* vatt = (const float*)d_in[3];
  const float* cnnW = (const float*)d_in[4];
  const float* cnnb = (const float*)d_in[5];
  float* out = (float*)d_out;

  char* ws = (char*)d_ws;
  u16*   Xb  = (u16*)ws;                            // 32768*512*2  =  33,554,432 B
  u16*   Wt1 = (u16*)(ws + 33554432);               // 1024*512*2   =   1,048,576 B
  u16*   Wt2 = (u16*)(ws + 34603008);               // 512*2560*2   =   2,621,440 B
  u16*   QKb = (u16*)(ws + 37224448);               // 32768*1024*2 =  67,108,864 B
  float* att = (float*)(ws + 104333312);            // 32768*5*4    =     655,360 B
                                                    // total ~105 MB

  cvtX<<<dim3(NROW * NF / 4 / 256), dim3(256), 0, stream>>>(X, Xb);
  cvtW<<<dim3((1024 * 512 + 512 * K2) / 256), dim3(256), 0, stream>>>(Wq, Wk, cnnW, Wt1, Wt2);
  gemm_qk<<<dim3(2048), dim3(512), 0, stream>>>(Xb, Wt1, QKb);
  scores_att<<<dim3(NROW / 4), dim3(256), 0, stream>>>(QKb, vatt, att);
  gemm_out<<<dim3(1024), dim3(512), 0, stream>>>(Xb, Wt2, att, cnnb, out);
}

// Round 7
// 210.721 us; speedup vs baseline: 1.0212x; 1.0212x over previous
//
#include <hip/hip_runtime.h>
#include <stdint.h>
#include <stddef.h>

typedef unsigned short u16;
typedef __attribute__((ext_vector_type(8))) short s16x8;    // bf16 MFMA A/B frag (4 VGPR)
typedef __attribute__((ext_vector_type(8))) unsigned short u16x8;
typedef __attribute__((ext_vector_type(4))) unsigned short u16x4;
typedef __attribute__((ext_vector_type(4))) float f32x4;

typedef __attribute__((address_space(3))) void* as3_void_p;
typedef const __attribute__((address_space(1))) void* as1_cvoid_p;

#define GLD16(gp, lp) __builtin_amdgcn_global_load_lds((as1_cvoid_p)(gp), (as3_void_p)(lp), 16, 0, 0)

enum {
  NS = 2048, NF = 512, NH = 512, NW = 5,
  NROW = 32768,            // B*S
  K2 = NW * NF             // 2560
};

__device__ __forceinline__ u16 f2bf(float f) {
  unsigned u = __float_as_uint(f);
  u += 0x7FFFu + ((u >> 16) & 1u);     // round-to-nearest-even
  return (u16)(u >> 16);
}
__device__ __forceinline__ float bf2f(u16 v) {
  return __uint_as_float(((unsigned)v) << 16);
}

// ---------------- conversion kernels ----------------

__global__ __launch_bounds__(256) void cvtX(const float* __restrict__ X, u16* __restrict__ Xb) {
  int i = blockIdx.x * 256 + threadIdx.x;          // 0 .. NROW*NF/4
  f32x4 v = ((const f32x4*)X)[i];
  u16x4 o;
  o.x = f2bf(v.x); o.y = f2bf(v.y); o.z = f2bf(v.z); o.w = f2bf(v.w);
  ((u16x4*)Xb)[i] = o;
}

// Wt1[j][f]: j<512 -> Wq[:,j]; else Wk[:,j-512].  Wt2[h][k] = cnn_W[k][h], k = w*512+f.
__global__ __launch_bounds__(256) void cvtW(const float* __restrict__ Wq, const float* __restrict__ Wk,
                                            const float* __restrict__ cnnW,
                                            u16* __restrict__ Wt1, u16* __restrict__ Wt2) {
  int i = blockIdx.x * 256 + threadIdx.x;          // 0 .. 1024*512 + 512*2560
  if (i < 1024 * 512) {
    int j = i >> 9, f = i & 511;
    float v = (j < 512) ? Wq[(size_t)f * 512 + j] : Wk[(size_t)f * 512 + (j - 512)];
    Wt1[i] = f2bf(v);
  } else {
    int t = i - 1024 * 512;                        // < 512*2560
    int h = t / K2, k = t % K2;
    Wt2[t] = f2bf(cnnW[(size_t)k * 512 + h]);
  }
}

// ---------------- GEMM1: QKb[n][0:1024] = Xb @ Wt1^T  (bf16 out) ----------------
// 128x128 block tile, 8 waves (2x4, wave tile 64x32), BK=128 (halves barrier-drain count),
// single-buffer LDS, T2 XOR-swizzle via pre-swizzled global source (rule #21).
// LDS rows are 256B; tile (row, cb) lives at byte row*256 + (cb ^ ((row&7)<<4)).

__global__ __launch_bounds__(512, 4) void gemm_qk(const u16* __restrict__ Xb,
                                                  const u16* __restrict__ Wt1,
                                                  u16* __restrict__ QKb) {
  __shared__ u16 As[128 * 128];                    // 32 KB
  __shared__ u16 Bs[128 * 128];                    // 32 KB
  const int tid  = threadIdx.x;
  const int lane = tid & 63, wid = tid >> 6;
  const int wr = wid >> 2, wc = wid & 3;           // 2 x 4 wave grid
  const int fr = lane & 15, fq = lane >> 4;
  // XCD-chunk swizzle: 2048 blocks, one XCD keeps contiguous row-panels
  const int wgid = (blockIdx.x & 7) * 256 + (blockIdx.x >> 3);
  const int brow = (wgid >> 3) * 128;
  const int bcol = (wgid & 7) * 128;

  // staging geometry: chunk c (8KB = 32 rows) at LDS byte c*8192 + tid*16;
  // row = c*32 + (tid>>4), colbyte = (tid&15)*16, source col = colbyte ^ ((row&7)<<4)
  const int rsub = tid >> 4;                                   // 0..31
  const int scb  = ((tid & 15) << 4) ^ ((rsub & 7) << 4);      // swizzled source column byte
  const char* gA[4];
  const char* gB[4];
#pragma unroll
  for (int c = 0; c < 4; ++c) {
    gA[c] = (const char*)(Xb  + (size_t)(brow + c * 32 + rsub) * NF) + scb;
    gB[c] = (const char*)(Wt1 + (size_t)(bcol + c * 32 + rsub) * NF) + scb;
  }

  f32x4 acc[4][2] = {};

  for (int kt = 0; kt < 4; ++kt) {                 // K-step 128
    const int ko = kt * 256;                       // byte offset along K
#pragma unroll
    for (int c = 0; c < 4; ++c) {
      GLD16(gA[c] + ko, (char*)As + c * 8192 + tid * 16);
      GLD16(gB[c] + ko, (char*)Bs + c * 8192 + tid * 16);
    }
    __syncthreads();
#pragma unroll
    for (int kk = 0; kk < 4; ++kk) {
      s16x8 af[4], bfr[2];
#pragma unroll
      for (int m = 0; m < 4; ++m) {
        int row = wr * 64 + m * 16 + fr;
        af[m] = *(const s16x8*)((const char*)As + row * 256 + ((kk * 64 + fq * 16) ^ ((row & 7) << 4)));
      }
#pragma unroll
      for (int n = 0; n < 2; ++n) {
        int row = wc * 32 + n * 16 + fr;
        bfr[n] = *(const s16x8*)((const char*)Bs + row * 256 + ((kk * 64 + fq * 16) ^ ((row & 7) << 4)));
      }
#pragma unroll
      for (int m = 0; m < 4; ++m)
#pragma unroll
        for (int n = 0; n < 2; ++n)
          acc[m][n] = __builtin_amdgcn_mfma_f32_16x16x32_bf16(af[m], bfr[n], acc[m][n], 0, 0, 0);
    }
    __syncthreads();
  }

#pragma unroll
  for (int m = 0; m < 4; ++m)
#pragma unroll
    for (int n = 0; n < 2; ++n)
#pragma unroll
      for (int r = 0; r < 4; ++r) {
        int row = brow + wr * 64 + m * 16 + fq * 4 + r;
        int col = bcol + wc * 32 + n * 16 + fr;
        QKb[(size_t)row * 1024 + col] = f2bf(acc[m][n][r]);
      }
}

// ---------------- scores + softmax -> att[n][5] ----------------

__global__ __launch_bounds__(256) void scores_att(const u16* __restrict__ QKb,
                                                  const float* __restrict__ vatt,
                                                  float* __restrict__ att) {
  const int lane = threadIdx.x & 63;
  const int wid  = threadIdx.x >> 6;
  const int n = blockIdx.x * 4 + wid;
  const int s = n & (NS - 1);
  const int h0 = lane * 8;

  u16x8 qv = *(const u16x8*)(QKb + (size_t)n * 1024 + h0);
  f32x4 va0 = *(const f32x4*)(vatt + h0);
  f32x4 va1 = *(const f32x4*)(vatt + h0 + 4);
  float q[8], vv[8];
#pragma unroll
  for (int j = 0; j < 8; ++j) q[j] = bf2f(qv[j]);
  vv[0] = va0.x; vv[1] = va0.y; vv[2] = va0.z; vv[3] = va0.w;
  vv[4] = va1.x; vv[5] = va1.y; vv[6] = va1.z; vv[7] = va1.w;

  float sc[5];
#pragma unroll
  for (int w = 0; w < 5; ++w) {
    int sp = s + w - 2;
    u16x8 kv = {0, 0, 0, 0, 0, 0, 0, 0};
    if (sp >= 0 && sp < NS)
      kv = *(const u16x8*)(QKb + (size_t)(n + w - 2) * 1024 + 512 + h0);
    float acc = 0.f;
#pragma unroll
    for (int j = 0; j < 8; ++j) {
      float x = q[j] + bf2f(kv[j]);
      x = fminf(fmaxf(x, -15.f), 15.f);
      float e = __expf(2.f * x);
      acc += vv[j] * ((e - 1.f) / (e + 1.f));     // tanh(x)
    }
    sc[w] = acc;
  }
#pragma unroll
  for (int w = 0; w < 5; ++w)
#pragma unroll
    for (int o = 32; o > 0; o >>= 1)
      sc[w] += __shfl_xor(sc[w], o, 64);

  if (lane == 0) {
    float m = sc[0];
#pragma unroll
    for (int w = 1; w < 5; ++w) m = fmaxf(m, sc[w]);
    float e[5], sum = 0.f;
#pragma unroll
    for (int w = 0; w < 5; ++w) { e[w] = __expf(sc[w] - m); sum += e[w]; }
    float inv = 1.f / sum;
#pragma unroll
    for (int w = 0; w < 5; ++w) att[(size_t)n * 5 + w] = e[w] * inv;
  }
}

// ---------------- GEMM2 (fold epilogue): out[n][h] = b[h] + sum_w att[n][w]*(X[n+w-2]@W_w)[h] ----
// 128x128 block tile, 8 waves (2x4, wave tile 64x32), BK=128 single-buffer (r5 structure,
// half the barrier drains). Per w: A = unscaled shifted Xb rows (pure global_load_lds,
// hoisted bases); after each w's 4 K-steps, fold acc into accOut with att[n][w]
// (OOB rows weight 0, row indices clamped in-bounds).

__global__ __launch_bounds__(512, 4) void gemm_out(const u16* __restrict__ Xb,
                                                   const u16* __restrict__ Wt2,
                                                   const float* __restrict__ att,
                                                   const float* __restrict__ cnnb,
                                                   float* __restrict__ out) {
  __shared__ u16 As[128 * 128];                    // 32 KB
  __shared__ u16 Bs[128 * 128];                    // 32 KB
  __shared__ float att_s[128 * 5];
  const int tid  = threadIdx.x;
  const int lane = tid & 63, wid = tid >> 6;
  const int wr = wid >> 2, wc = wid & 3;           // 2 x 4 wave grid, wave tile 64x32
  const int fr = lane & 15, fq = lane >> 4;
  // XCD-chunk swizzle: 1024 blocks, contiguous row-panels per XCD (col-fast within)
  const int wgid = (blockIdx.x & 7) * 128 + (blockIdx.x >> 3);
  const int brow = (wgid >> 2) * 128;
  const int bcol = (wgid & 3) * 128;

  if (tid < 128) {
    int s = (brow + tid) & (NS - 1);
#pragma unroll
    for (int w = 0; w < 5; ++w) {
      int sp = s + w - 2;
      att_s[tid * 5 + w] = (sp >= 0 && sp < NS) ? att[(size_t)(brow + tid) * 5 + w] : 0.f;
    }
  }

  // staging geometry (see gemm_qk)
  const int rsub = tid >> 4;                                   // 0..31
  const int scb  = ((tid & 15) << 4) ^ ((rsub & 7) << 4);      // swizzled source column byte
  const char* gB[4];
#pragma unroll
  for (int c = 0; c < 4; ++c)
    gB[c] = (const char*)(Wt2 + (size_t)(bcol + c * 32 + rsub) * K2) + scb;

  f32x4 acc[4][2] = {};
  f32x4 accOut[4][2] = {};

  for (int w = 0; w < 5; ++w) {
    // per-w A row bases (clamped; invalid rows get fold weight 0)
    const char* gA[4];
#pragma unroll
    for (int c = 0; c < 4; ++c) {
      int g = brow + c * 32 + rsub + w - 2;
      g = g < 0 ? 0 : (g >= NROW ? NROW - 1 : g);
      gA[c] = (const char*)(Xb + (size_t)g * NF) + scb;
    }
    const int wo = w * 1024;                       // byte offset into Wt2 row for this w

    for (int kt = 0; kt < 4; ++kt) {               // K-step 128
      const int ko = kt * 256;
#pragma unroll
      for (int c = 0; c < 4; ++c) {
        GLD16(gA[c] + ko,      (char*)As + c * 8192 + tid * 16);
        GLD16(gB[c] + wo + ko, (char*)Bs + c * 8192 + tid * 16);
      }
      __syncthreads();
#pragma unroll
      for (int kk = 0; kk < 4; ++kk) {
        s16x8 af[4], bfr[2];
#pragma unroll
        for (int m = 0; m < 4; ++m) {
          int row = wr * 64 + m * 16 + fr;
          af[m] = *(const s16x8*)((const char*)As + row * 256 + ((kk * 64 + fq * 16) ^ ((row & 7) << 4)));
        }
#pragma unroll
        for (int n = 0; n < 2; ++n) {
          int row = wc * 32 + n * 16 + fr;
          bfr[n] = *(const s16x8*)((const char*)Bs + row * 256 + ((kk * 64 + fq * 16) ^ ((row & 7) << 4)));
        }
#pragma unroll
        for (int m = 0; m < 4; ++m)
#pragma unroll
          for (int n = 0; n < 2; ++n)
            acc[m][n] = __builtin_amdgcn_mfma_f32_16x16x32_bf16(af[m], bfr[n], acc[m][n], 0, 0, 0);
      }
      __syncthreads();
    }
    // fold: accOut += att[row][w] * acc; acc = 0  (registers + att_s only)
#pragma unroll
    for (int m = 0; m < 4; ++m) {
      float a0 = att_s[(wr * 64 + m * 16 + fq * 4 + 0) * 5 + w];
      float a1 = att_s[(wr * 64 + m * 16 + fq * 4 + 1) * 5 + w];
      float a2 = att_s[(wr * 64 + m * 16 + fq * 4 + 2) * 5 + w];
      float a3 = att_s[(wr * 64 + m * 16 + fq * 4 + 3) * 5 + w];
#pragma unroll
      for (int n = 0; n < 2; ++n) {
        accOut[m][n][0] += a0 * acc[m][n][0];
        accOut[m][n][1] += a1 * acc[m][n][1];
        accOut[m][n][2] += a2 * acc[m][n][2];
        accOut[m][n][3] += a3 * acc[m][n][3];
        acc[m][n] = f32x4{0.f, 0.f, 0.f, 0.f};
      }
    }
  }

#pragma unroll
  for (int m = 0; m < 4; ++m)
#pragma unroll
    for (int n = 0; n < 2; ++n)
#pragma unroll
      for (int r = 0; r < 4; ++r) {
        int row = brow + wr * 64 + m * 16 + fq * 4 + r;
        int col = bcol + wc * 32 + n * 16 + fr;
        out[(size_t)row * NH + col] = accOut[m][n][r] + cnnb[col];
      }
}

// ---------------- launch ----------------

extern "C" void kernel_launch(void* const* d_in, const int* in_sizes, int n_in,
                              void* d_out, int out_size, void* d_ws, size_t ws_size,
                              hipStream_t stream) {
  const float* X    = (const float*)d_in[0];
  const float* Wq   = (const float*)d_in[1];
  const float* Wk   = (const float*)d_in[2];
  const float* vatt = (const float*)d_in[3];
  const float* cnnW = (const float*)d_in[4];
  const float* cnnb = (const float*)d_in[5];
  float* out = (float*)d_out;

  char* ws = (char*)d_ws;
  u16*   Xb  = (u16*)ws;                            // 32768*512*2  =  33,554,432 B
  u16*   Wt1 = (u16*)(ws + 33554432);               // 1024*512*2   =   1,048,576 B
  u16*   Wt2 = (u16*)(ws + 34603008);               // 512*2560*2   =   2,621,440 B
  u16*   QKb = (u16*)(ws + 37224448);               // 32768*1024*2 =  67,108,864 B
  float* att = (float*)(ws + 104333312);            // 32768*5*4    =     655,360 B
                                                    // total ~105 MB

  cvtX<<<dim3(NROW * NF / 4 / 256), dim3(256), 0, stream>>>(X, Xb);
  cvtW<<<dim3((1024 * 512 + 512 * K2) / 256), dim3(256), 0, stream>>>(Wq, Wk, cnnW, Wt1, Wt2);
  gemm_qk<<<dim3(2048), dim3(512), 0, stream>>>(Xb, Wt1, QKb);
  scores_att<<<dim3(NROW / 4), dim3(256), 0, stream>>>(QKb, vatt, att);
  gemm_out<<<dim3(1024), dim3(512), 0, stream>>>(Xb, Wt2, att, cnnb, out);
}

// Round 9
// 201.970 us; speedup vs baseline: 1.0655x; 1.0433x over previous
//
#include <hip/hip_runtime.h>
#include <stdint.h>
#include <stddef.h>

typedef unsigned short u16;
typedef __attribute__((ext_vector_type(8))) short s16x8;    // bf16 MFMA A/B frag (4 VGPR)
typedef __attribute__((ext_vector_type(8))) unsigned short u16x8;
typedef __attribute__((ext_vector_type(4))) unsigned short u16x4;
typedef __attribute__((ext_vector_type(4))) float f32x4;

typedef __attribute__((address_space(3))) void* as3_void_p;
typedef const __attribute__((address_space(1))) void* as1_cvoid_p;

#define GLD16(gp, lp) __builtin_amdgcn_global_load_lds((as1_cvoid_p)(gp), (as3_void_p)(lp), 16, 0, 0)

enum {
  NS = 2048, NF = 512, NH = 512, NW = 5,
  NROW = 32768,                    // B*S
  K2 = NW * NF,                    // 2560
  XBLOCKS = NROW * NF / 4 / 256,   // 16384
  W_ELEMS = 1024 * 512 + 512 * K2, // 1,835,008
  WBLOCKS = (W_ELEMS + 255) / 256  // 7168
};

__device__ __forceinline__ u16 f2bf(float f) {
  unsigned u = __float_as_uint(f);
  u += 0x7FFFu + ((u >> 16) & 1u);     // round-to-nearest-even
  return (u16)(u >> 16);
}
__device__ __forceinline__ float bf2f(u16 v) {
  return __uint_as_float(((unsigned)v) << 16);
}

// ---------------- merged conversion kernel ----------------
// blocks [0, XBLOCKS): Xb bf16 cast (vector f32x4 -> u16x4)
// blocks [XBLOCKS, XBLOCKS+WBLOCKS): Wt1 (Wq|Wk transposed) and Wt2 (cnn_W transposed)

__global__ __launch_bounds__(256) void cvt_all(const float* __restrict__ X,
                                               const float* __restrict__ Wq,
                                               const float* __restrict__ Wk,
                                               const float* __restrict__ cnnW,
                                               u16* __restrict__ Xb,
                                               u16* __restrict__ Wt1,
                                               u16* __restrict__ Wt2) {
  int b = blockIdx.x;
  if (b < XBLOCKS) {
    int i = b * 256 + threadIdx.x;                 // 0 .. NROW*NF/4
    f32x4 v = ((const f32x4*)X)[i];
    u16x4 o;
    o.x = f2bf(v.x); o.y = f2bf(v.y); o.z = f2bf(v.z); o.w = f2bf(v.w);
    ((u16x4*)Xb)[i] = o;
  } else {
    int i = (b - XBLOCKS) * 256 + threadIdx.x;     // 0 .. W_ELEMS
    if (i >= W_ELEMS) return;
    if (i < 1024 * 512) {
      int j = i >> 9, f = i & 511;
      float v = (j < 512) ? Wq[(size_t)f * 512 + j] : Wk[(size_t)f * 512 + (j - 512)];
      Wt1[i] = f2bf(v);
    } else {
      int t = i - 1024 * 512;                      // < 512*2560
      int h = t / K2, k = t % K2;
      Wt2[t] = f2bf(cnnW[(size_t)k * 512 + h]);
    }
  }
}

// ---------------- GEMM1: QKb[n][0:1024] = Xb @ Wt1^T  (bf16 out) ----------------
// 128x128 block tile, 8 waves (2x4, wave tile 64x32), BK=64, single-buffer LDS,
// T2 XOR-swizzle via pre-swizzled global source (rule #21): tile (row, cb) lives
// at LDS byte row*128 + (cb ^ ((row&7)<<4)) -> conflict-free at 128B row stride.

__global__ __launch_bounds__(512, 4) void gemm_qk(const u16* __restrict__ Xb,
                                                  const u16* __restrict__ Wt1,
                                                  u16* __restrict__ QKb) {
  __shared__ u16 As[128 * 64];                     // 16 KB
  __shared__ u16 Bs[128 * 64];                     // 16 KB
  const int tid  = threadIdx.x;
  const int lane = tid & 63, wid = tid >> 6;
  const int wr = wid >> 2, wc = wid & 3;           // 2 x 4 wave grid
  const int fr = lane & 15, fq = lane >> 4;
  // XCD-chunk swizzle: 2048 blocks, one XCD keeps contiguous row-panels
  const int wgid = (blockIdx.x & 7) * 256 + (blockIdx.x >> 3);
  const int brow = (wgid >> 3) * 128;
  const int bcol = (wgid & 7) * 128;

  // tid-static staging geometry (4 x GLD16 per thread per K-step)
  const int rsub = tid >> 3;                                   // 0..63
  const int cb   = (((tid & 7) ^ (rsub & 7)) << 4);            // swizzled source column byte
  const char* gA0 = (const char*)(Xb  + (size_t)(brow + rsub) * NF) + cb;
  const char* gA1 = (const char*)(Xb  + (size_t)(brow + 64 + rsub) * NF) + cb;
  const char* gB0 = (const char*)(Wt1 + (size_t)(bcol + rsub) * NF) + cb;
  const char* gB1 = (const char*)(Wt1 + (size_t)(bcol + 64 + rsub) * NF) + cb;

  f32x4 acc[4][2] = {};

  for (int kt = 0; kt < 8; ++kt) {
    const int ko = kt * 128;
    GLD16(gA0 + ko, (char*)As + tid * 16);
    GLD16(gA1 + ko, (char*)As + 8192 + tid * 16);
    GLD16(gB0 + ko, (char*)Bs + tid * 16);
    GLD16(gB1 + ko, (char*)Bs + 8192 + tid * 16);
    __syncthreads();
#pragma unroll
    for (int kk = 0; kk < 2; ++kk) {
      s16x8 af[4], bfr[2];
#pragma unroll
      for (int m = 0; m < 4; ++m) {
        int row = wr * 64 + m * 16 + fr;
        af[m] = *(const s16x8*)((const char*)As + row * 128 + ((kk * 64 + fq * 16) ^ ((row & 7) << 4)));
      }
#pragma unroll
      for (int n = 0; n < 2; ++n) {
        int row = wc * 32 + n * 16 + fr;
        bfr[n] = *(const s16x8*)((const char*)Bs + row * 128 + ((kk * 64 + fq * 16) ^ ((row & 7) << 4)));
      }
#pragma unroll
      for (int m = 0; m < 4; ++m)
#pragma unroll
        for (int n = 0; n < 2; ++n)
          acc[m][n] = __builtin_amdgcn_mfma_f32_16x16x32_bf16(af[m], bfr[n], acc[m][n], 0, 0, 0);
    }
    __syncthreads();
  }

#pragma unroll
  for (int m = 0; m < 4; ++m)
#pragma unroll
    for (int n = 0; n < 2; ++n)
#pragma unroll
      for (int r = 0; r < 4; ++r) {
        int row = brow + wr * 64 + m * 16 + fq * 4 + r;
        int col = bcol + wc * 32 + n * 16 + fr;
        QKb[(size_t)row * 1024 + col] = f2bf(acc[m][n][r]);
      }
}

// ---------------- scores + softmax -> att[n][5] ----------------
// one wave per row n, h = lane*8..+7 vectorized. XCD-chunked grid: each XCD owns a
// contiguous 4096-row range -> the 5x-overlapping K-row windows become L2-resident.

__global__ __launch_bounds__(256) void scores_att(const u16* __restrict__ QKb,
                                                  const float* __restrict__ vatt,
                                                  float* __restrict__ att) {
  const int lane = threadIdx.x & 63;
  const int wid  = threadIdx.x >> 6;
  const int wgid = (blockIdx.x & 7) * 1024 + (blockIdx.x >> 3);   // 8192 blocks chunked
  const int n = wgid * 4 + wid;
  const int s = n & (NS - 1);
  const int h0 = lane * 8;

  u16x8 qv = *(const u16x8*)(QKb + (size_t)n * 1024 + h0);
  f32x4 va0 = *(const f32x4*)(vatt + h0);
  f32x4 va1 = *(const f32x4*)(vatt + h0 + 4);
  float q[8], vv[8];
#pragma unroll
  for (int j = 0; j < 8; ++j) q[j] = bf2f(qv[j]);
  vv[0] = va0.x; vv[1] = va0.y; vv[2] = va0.z; vv[3] = va0.w;
  vv[4] = va1.x; vv[5] = va1.y; vv[6] = va1.z; vv[7] = va1.w;

  float sc[5];
#pragma unroll
  for (int w = 0; w < 5; ++w) {
    int sp = s + w - 2;
    u16x8 kv = {0, 0, 0, 0, 0, 0, 0, 0};
    if (sp >= 0 && sp < NS)
      kv = *(const u16x8*)(QKb + (size_t)(n + w - 2) * 1024 + 512 + h0);
    float acc = 0.f;
#pragma unroll
    for (int j = 0; j < 8; ++j) {
      float x = q[j] + bf2f(kv[j]);
      x = fminf(fmaxf(x, -15.f), 15.f);
      float e = __expf(2.f * x);
      acc += vv[j] * ((e - 1.f) / (e + 1.f));     // tanh(x)
    }
    sc[w] = acc;
  }
#pragma unroll
  for (int w = 0; w < 5; ++w)
#pragma unroll
    for (int o = 32; o > 0; o >>= 1)
      sc[w] += __shfl_xor(sc[w], o, 64);

  if (lane == 0) {
    float m = sc[0];
#pragma unroll
    for (int w = 1; w < 5; ++w) m = fmaxf(m, sc[w]);
    float e[5], sum = 0.f;
#pragma unroll
    for (int w = 0; w < 5; ++w) { e[w] = __expf(sc[w] - m); sum += e[w]; }
    float inv = 1.f / sum;
#pragma unroll
    for (int w = 0; w < 5; ++w) att[(size_t)n * 5 + w] = e[w] * inv;
  }
}

// ---------------- GEMM2 (fold epilogue): out[n][h] = b[h] + sum_w att[n][w]*(X[n+w-2]@W_w)[h] ----
// Round-5 proven structure: 128x128 block tile, 8 waves (2x4, wave tile 64x32), BK=64
// single-buffer, hoisted per-w A bases. After each w's 8 K-steps, fold acc into accOut
// with att[n][w] (OOB rows weight 0, row indices clamped in-bounds).

__global__ __launch_bounds__(512, 4) void gemm_out(const u16* __restrict__ Xb,
                                                   const u16* __restrict__ Wt2,
                                                   const float* __restrict__ att,
                                                   const float* __restrict__ cnnb,
                                                   float* __restrict__ out) {
  __shared__ u16 As[128 * 64];                     // 16 KB
  __shared__ u16 Bs[128 * 64];                     // 16 KB
  __shared__ float att_s[128 * 5];
  const int tid  = threadIdx.x;
  const int lane = tid & 63, wid = tid >> 6;
  const int wr = wid >> 2, wc = wid & 3;           // 2 x 4 wave grid, wave tile 64x32
  const int fr = lane & 15, fq = lane >> 4;
  // XCD-chunk swizzle: 1024 blocks, contiguous row-panels per XCD (col-fast within)
  const int wgid = (blockIdx.x & 7) * 128 + (blockIdx.x >> 3);
  const int brow = (wgid >> 2) * 128;
  const int bcol = (wgid & 3) * 128;

  if (tid < 128) {
    int s = (brow + tid) & (NS - 1);
#pragma unroll
    for (int w = 0; w < 5; ++w) {
      int sp = s + w - 2;
      att_s[tid * 5 + w] = (sp >= 0 && sp < NS) ? att[(size_t)(brow + tid) * 5 + w] : 0.f;
    }
  }

  // tid-static staging geometry
  const int rsub = tid >> 3;                                   // 0..63
  const int cb   = (((tid & 7) ^ (rsub & 7)) << 4);            // swizzled source column byte
  const char* gB0 = (const char*)(Wt2 + (size_t)(bcol + rsub) * K2) + cb;
  const char* gB1 = (const char*)(Wt2 + (size_t)(bcol + 64 + rsub) * K2) + cb;

  f32x4 acc[4][2] = {};
  f32x4 accOut[4][2] = {};

  for (int w = 0; w < 5; ++w) {
    // per-w A row bases (clamped; invalid rows get fold weight 0)
    int g0 = brow + rsub + w - 2;
    int g1 = brow + 64 + rsub + w - 2;
    g0 = g0 < 0 ? 0 : (g0 >= NROW ? NROW - 1 : g0);
    g1 = g1 < 0 ? 0 : (g1 >= NROW ? NROW - 1 : g1);
    const char* gA0 = (const char*)(Xb + (size_t)g0 * NF) + cb;
    const char* gA1 = (const char*)(Xb + (size_t)g1 * NF) + cb;
    const char* gBw0 = gB0 + w * 1024;
    const char* gBw1 = gB1 + w * 1024;

    for (int kt = 0; kt < 8; ++kt) {
      const int ko = kt * 128;
      GLD16(gA0  + ko, (char*)As + tid * 16);
      GLD16(gA1  + ko, (char*)As + 8192 + tid * 16);
      GLD16(gBw0 + ko, (char*)Bs + tid * 16);
      GLD16(gBw1 + ko, (char*)Bs + 8192 + tid * 16);
      __syncthreads();
#pragma unroll
      for (int kk = 0; kk < 2; ++kk) {
        s16x8 af[4], bfr[2];
#pragma unroll
        for (int m = 0; m < 4; ++m) {
          int row = wr * 64 + m * 16 + fr;
          af[m] = *(const s16x8*)((const char*)As + row * 128 + ((kk * 64 + fq * 16) ^ ((row & 7) << 4)));
        }
#pragma unroll
        for (int n = 0; n < 2; ++n) {
          int row = wc * 32 + n * 16 + fr;
          bfr[n] = *(const s16x8*)((const char*)Bs + row * 128 + ((kk * 64 + fq * 16) ^ ((row & 7) << 4)));
        }
#pragma unroll
        for (int m = 0; m < 4; ++m)
#pragma unroll
          for (int n = 0; n < 2; ++n)
            acc[m][n] = __builtin_amdgcn_mfma_f32_16x16x32_bf16(af[m], bfr[n], acc[m][n], 0, 0, 0);
      }
      __syncthreads();
    }
    // fold: accOut += att[row][w] * acc; acc = 0  (registers + att_s only)
#pragma unroll
    for (int m = 0; m < 4; ++m) {
      float a0 = att_s[(wr * 64 + m * 16 + fq * 4 + 0) * 5 + w];
      float a1 = att_s[(wr * 64 + m * 16 + fq * 4 + 1) * 5 + w];
      float a2 = att_s[(wr * 64 + m * 16 + fq * 4 + 2) * 5 + w];
      float a3 = att_s[(wr * 64 + m * 16 + fq * 4 + 3) * 5 + w];
#pragma unroll
      for (int n = 0; n < 2; ++n) {
        accOut[m][n][0] += a0 * acc[m][n][0];
        accOut[m][n][1] += a1 * acc[m][n][1];
        accOut[m][n][2] += a2 * acc[m][n][2];
        accOut[m][n][3] += a3 * acc[m][n][3];
        acc[m][n] = f32x4{0.f, 0.f, 0.f, 0.f};
      }
    }
  }

#pragma unroll
  for (int m = 0; m < 4; ++m)
#pragma unroll
    for (int n = 0; n < 2; ++n)
#pragma unroll
      for (int r = 0; r < 4; ++r) {
        int row = brow + wr * 64 + m * 16 + fq * 4 + r;
        int col = bcol + wc * 32 + n * 16 + fr;
        out[(size_t)row * NH + col] = accOut[m][n][r] + cnnb[col];
      }
}

// ---------------- launch ----------------

extern "C" void kernel_launch(void* const* d_in, const int* in_sizes, int n_in,
                              void* d_out, int out_size, void* d_ws, size_t ws_size,
                              hipStream_t stream) {
  const float* X    = (const float*)d_in[0];
  const float* Wq   = (const float*)d_in[1];
  const float* Wk   = (const float*)d_in[2];
  const float* vatt = (const float*)d_in[3];
  const float* cnnW = (const float*)d_in[4];
  const float* cnnb = (const float*)d_in[5];
  float* out = (float*)d_out;

  char* ws = (char*)d_ws;
  u16*   Xb  = (u16*)ws;                            // 32768*512*2  =  33,554,432 B
  u16*   Wt1 = (u16*)(ws + 33554432);               // 1024*512*2   =   1,048,576 B
  u16*   Wt2 = (u16*)(ws + 34603008);               // 512*2560*2   =   2,621,440 B
  u16*   QKb = (u16*)(ws + 37224448);               // 32768*1024*2 =  67,108,864 B
  float* att = (float*)(ws + 104333312);            // 32768*5*4    =     655,360 B
                                                    // total ~105 MB

  cvt_all<<<dim3(XBLOCKS + WBLOCKS), dim3(256), 0, stream>>>(X, Wq, Wk, cnnW, Xb, Wt1, Wt2);
  gemm_qk<<<dim3(2048), dim3(512), 0, stream>>>(Xb, Wt1, QKb);
  scores_att<<<dim3(NROW / 4), dim3(256), 0, stream>>>(QKb, vatt, att);
  gemm_out<<<dim3(1024), dim3(512), 0, stream>>>(Xb, Wt2, att, cnnb, out);
}

// Round 10
// 200.961 us; speedup vs baseline: 1.0708x; 1.0050x over previous
//
#include <hip/hip_runtime.h>
#include <stdint.h>
#include <stddef.h>

typedef unsigned short u16;
typedef __attribute__((ext_vector_type(8))) short s16x8;    // bf16 MFMA A/B frag (4 VGPR)
typedef __attribute__((ext_vector_type(8))) unsigned short u16x8;
typedef __attribute__((ext_vector_type(4))) unsigned short u16x4;
typedef __attribute__((ext_vector_type(4))) float f32x4;

typedef __attribute__((address_space(3))) void* as3_void_p;
typedef const __attribute__((address_space(1))) void* as1_cvoid_p;

#define GLD16(gp, lp) __builtin_amdgcn_global_load_lds((as1_cvoid_p)(gp), (as3_void_p)(lp), 16, 0, 0)

enum {
  NS = 2048, NF = 512, NH = 512, NW = 5,
  NROW = 32768,                    // B*S
  K2 = NW * NF,                    // 2560
  XBLOCKS = NROW * NF / 4 / 256,   // 16384
  W_ELEMS = 1024 * 512 + 512 * K2, // 1,835,008
  WBLOCKS = (W_ELEMS + 255) / 256  // 7168
};

__device__ __forceinline__ u16 f2bf(float f) {
  unsigned u = __float_as_uint(f);
  u += 0x7FFFu + ((u >> 16) & 1u);     // round-to-nearest-even
  return (u16)(u >> 16);
}
__device__ __forceinline__ float bf2f(u16 v) {
  return __uint_as_float(((unsigned)v) << 16);
}

// ---------------- merged conversion kernel ----------------

__global__ __launch_bounds__(256) void cvt_all(const float* __restrict__ X,
                                               const float* __restrict__ Wq,
                                               const float* __restrict__ Wk,
                                               const float* __restrict__ cnnW,
                                               u16* __restrict__ Xb,
                                               u16* __restrict__ Wt1,
                                               u16* __restrict__ Wt2) {
  int b = blockIdx.x;
  if (b < XBLOCKS) {
    int i = b * 256 + threadIdx.x;                 // 0 .. NROW*NF/4
    f32x4 v = ((const f32x4*)X)[i];
    u16x4 o;
    o.x = f2bf(v.x); o.y = f2bf(v.y); o.z = f2bf(v.z); o.w = f2bf(v.w);
    ((u16x4*)Xb)[i] = o;
  } else {
    int i = (b - XBLOCKS) * 256 + threadIdx.x;     // 0 .. W_ELEMS
    if (i >= W_ELEMS) return;
    if (i < 1024 * 512) {
      int j = i >> 9, f = i & 511;
      float v = (j < 512) ? Wq[(size_t)f * 512 + j] : Wk[(size_t)f * 512 + (j - 512)];
      Wt1[i] = f2bf(v);
    } else {
      int t = i - 1024 * 512;                      // < 512*2560
      int h = t / K2, k = t % K2;
      Wt2[t] = f2bf(cnnW[(size_t)k * 512 + h]);
    }
  }
}

// ---------------- GEMM1: QKb[n][0:1024] = Xb @ Wt1^T  (bf16 out) ----------------
// Round-9 proven: 128x128 tile, 8 waves (2x4, wave tile 64x32), BK=64, single-buffer,
// T2 XOR-swizzle via pre-swizzled global source (rule #21).

__global__ __launch_bounds__(512, 4) void gemm_qk(const u16* __restrict__ Xb,
                                                  const u16* __restrict__ Wt1,
                                                  u16* __restrict__ QKb) {
  __shared__ u16 As[128 * 64];                     // 16 KB
  __shared__ u16 Bs[128 * 64];                     // 16 KB
  const int tid  = threadIdx.x;
  const int lane = tid & 63, wid = tid >> 6;
  const int wr = wid >> 2, wc = wid & 3;           // 2 x 4 wave grid
  const int fr = lane & 15, fq = lane >> 4;
  // XCD-chunk swizzle: 2048 blocks, one XCD keeps contiguous row-panels
  const int wgid = (blockIdx.x & 7) * 256 + (blockIdx.x >> 3);
  const int brow = (wgid >> 3) * 128;
  const int bcol = (wgid & 7) * 128;

  const int rsub = tid >> 3;                                   // 0..63
  const int cb   = (((tid & 7) ^ (rsub & 7)) << 4);            // swizzled source column byte
  const char* gA0 = (const char*)(Xb  + (size_t)(brow + rsub) * NF) + cb;
  const char* gA1 = (const char*)(Xb  + (size_t)(brow + 64 + rsub) * NF) + cb;
  const char* gB0 = (const char*)(Wt1 + (size_t)(bcol + rsub) * NF) + cb;
  const char* gB1 = (const char*)(Wt1 + (size_t)(bcol + 64 + rsub) * NF) + cb;

  f32x4 acc[4][2] = {};

  for (int kt = 0; kt < 8; ++kt) {
    const int ko = kt * 128;
    GLD16(gA0 + ko, (char*)As + tid * 16);
    GLD16(gA1 + ko, (char*)As + 8192 + tid * 16);
    GLD16(gB0 + ko, (char*)Bs + tid * 16);
    GLD16(gB1 + ko, (char*)Bs + 8192 + tid * 16);
    __syncthreads();
#pragma unroll
    for (int kk = 0; kk < 2; ++kk) {
      s16x8 af[4], bfr[2];
#pragma unroll
      for (int m = 0; m < 4; ++m) {
        int row = wr * 64 + m * 16 + fr;
        af[m] = *(const s16x8*)((const char*)As + row * 128 + ((kk * 64 + fq * 16) ^ ((row & 7) << 4)));
      }
#pragma unroll
      for (int n = 0; n < 2; ++n) {
        int row = wc * 32 + n * 16 + fr;
        bfr[n] = *(const s16x8*)((const char*)Bs + row * 128 + ((kk * 64 + fq * 16) ^ ((row & 7) << 4)));
      }
#pragma unroll
      for (int m = 0; m < 4; ++m)
#pragma unroll
        for (int n = 0; n < 2; ++n)
          acc[m][n] = __builtin_amdgcn_mfma_f32_16x16x32_bf16(af[m], bfr[n], acc[m][n], 0, 0, 0);
    }
    __syncthreads();
  }

#pragma unroll
  for (int m = 0; m < 4; ++m)
#pragma unroll
    for (int n = 0; n < 2; ++n)
#pragma unroll
      for (int r = 0; r < 4; ++r) {
        int row = brow + wr * 64 + m * 16 + fq * 4 + r;
        int col = bcol + wc * 32 + n * 16 + fr;
        QKb[(size_t)row * 1024 + col] = f2bf(acc[m][n][r]);
      }
}

// ---------------- scores + softmax -> att[n][5] ----------------

__global__ __launch_bounds__(256) void scores_att(const u16* __restrict__ QKb,
                                                  const float* __restrict__ vatt,
                                                  float* __restrict__ att) {
  const int lane = threadIdx.x & 63;
  const int wid  = threadIdx.x >> 6;
  const int wgid = (blockIdx.x & 7) * 1024 + (blockIdx.x >> 3);   // 8192 blocks chunked
  const int n = wgid * 4 + wid;
  const int s = n & (NS - 1);
  const int h0 = lane * 8;

  u16x8 qv = *(const u16x8*)(QKb + (size_t)n * 1024 + h0);
  f32x4 va0 = *(const f32x4*)(vatt + h0);
  f32x4 va1 = *(const f32x4*)(vatt + h0 + 4);
  float q[8], vv[8];
#pragma unroll
  for (int j = 0; j < 8; ++j) q[j] = bf2f(qv[j]);
  vv[0] = va0.x; vv[1] = va0.y; vv[2] = va0.z; vv[3] = va0.w;
  vv[4] = va1.x; vv[5] = va1.y; vv[6] = va1.z; vv[7] = va1.w;

  float sc[5];
#pragma unroll
  for (int w = 0; w < 5; ++w) {
    int sp = s + w - 2;
    u16x8 kv = {0, 0, 0, 0, 0, 0, 0, 0};
    if (sp >= 0 && sp < NS)
      kv = *(const u16x8*)(QKb + (size_t)(n + w - 2) * 1024 + 512 + h0);
    float acc = 0.f;
#pragma unroll
    for (int j = 0; j < 8; ++j) {
      float x = q[j] + bf2f(kv[j]);
      x = fminf(fmaxf(x, -15.f), 15.f);
      float e = __expf(2.f * x);
      acc += vv[j] * ((e - 1.f) / (e + 1.f));     // tanh(x)
    }
    sc[w] = acc;
  }
#pragma unroll
  for (int w = 0; w < 5; ++w)
#pragma unroll
    for (int o = 32; o > 0; o >>= 1)
      sc[w] += __shfl_xor(sc[w], o, 64);

  if (lane == 0) {
    float m = sc[0];
#pragma unroll
    for (int w = 1; w < 5; ++w) m = fmaxf(m, sc[w]);
    float e[5], sum = 0.f;
#pragma unroll
    for (int w = 0; w < 5; ++w) { e[w] = __expf(sc[w] - m); sum += e[w]; }
    float inv = 1.f / sum;
#pragma unroll
    for (int w = 0; w < 5; ++w) att[(size_t)n * 5 + w] = e[w] * inv;
  }
}

// ---------------- GEMM2 (fold + T4 counted-vmcnt pipeline) ----------------
// out[n][h] = b[h] + sum_w att[n][w]*(X[n+w-2]@W_w)[h]
// Round-9 geometry (128x128 tile, 8 waves 2x4, BK=64, XOR-swizzle) + double-buffered
// LDS with counted s_waitcnt vmcnt(4): stage(t+1) stays IN FLIGHT across both raw
// barriers and the MFMA phase; only one drain-0 (prologue). Hazards:
//   - stage(t+1) overwrites buf read at t-1: guarded by t-1's trailing barrier.
//   - ds_read(t) needs all waves' t-loads: per-wave vmcnt(4) + leading barrier.
//   - per-wave ds_reads retire before trailing barrier: lgkmcnt(0) precedes MFMA.

__global__ __launch_bounds__(512, 4) void gemm_out(const u16* __restrict__ Xb,
                                                   const u16* __restrict__ Wt2,
                                                   const float* __restrict__ att,
                                                   const float* __restrict__ cnnb,
                                                   float* __restrict__ out) {
  __shared__ u16 As[2][128 * 64];                  // 2 x 16 KB
  __shared__ u16 Bs[2][128 * 64];                  // 2 x 16 KB
  __shared__ float att_s[128 * 5];
  const int tid  = threadIdx.x;
  const int lane = tid & 63, wid = tid >> 6;
  const int wr = wid >> 2, wc = wid & 3;           // 2 x 4 wave grid, wave tile 64x32
  const int fr = lane & 15, fq = lane >> 4;
  // XCD-chunk swizzle: 1024 blocks, contiguous row-panels per XCD (col-fast within)
  const int wgid = (blockIdx.x & 7) * 128 + (blockIdx.x >> 3);
  const int brow = (wgid >> 2) * 128;
  const int bcol = (wgid & 3) * 128;

  if (tid < 128) {
    int s = (brow + tid) & (NS - 1);
#pragma unroll
    for (int w = 0; w < 5; ++w) {
      int sp = s + w - 2;
      att_s[tid * 5 + w] = (sp >= 0 && sp < NS) ? att[(size_t)(brow + tid) * 5 + w] : 0.f;
    }
  }

  // tid-static staging geometry
  const int rsub = tid >> 3;                                   // 0..63
  const int cb   = (((tid & 7) ^ (rsub & 7)) << 4);            // swizzled source column byte
  const char* gB0 = (const char*)(Wt2 + (size_t)(bcol + rsub) * K2) + cb;
  const char* gB1 = (const char*)(Wt2 + (size_t)(bcol + 64 + rsub) * K2) + cb;

  // per-w A row base (clamped; invalid rows get fold weight 0)
  auto abase = [&](int w, int add64) -> const char* {
    int g = brow + add64 + rsub + w - 2;
    g = g < 0 ? 0 : (g >= NROW ? NROW - 1 : g);
    return (const char*)(Xb + (size_t)g * NF) + cb;
  };

  f32x4 acc[4][2] = {};
  f32x4 accOut[4][2] = {};

  const char* gA0 = abase(0, 0);
  const char* gA1 = abase(0, 64);

  // prologue: stage (w=0, kt=0) into buf 0; single full drain (also covers att_s)
  GLD16(gA0, (char*)As[0] + tid * 16);
  GLD16(gA1, (char*)As[0] + 8192 + tid * 16);
  GLD16(gB0, (char*)Bs[0] + tid * 16);
  GLD16(gB1, (char*)Bs[0] + 8192 + tid * 16);
  __syncthreads();

  int cur = 0;
  for (int w = 0; w < 5; ++w) {
    const char* gBw0 = gB0 + w * 1024;
    const char* gBw1 = gB1 + w * 1024;
    const char* nA0 = (w < 4) ? abase(w + 1, 0)  : gA0;   // next-w bases (once per w)
    const char* nA1 = (w < 4) ? abase(w + 1, 64) : gA1;

    for (int kt = 0; kt < 8; ++kt) {
      const bool last = (w == 4) && (kt == 7);
      const int nb = cur ^ 1;
      if (!last) {
        if (kt < 7) {                              // stage (w, kt+1)
          const int ko = (kt + 1) * 128;
          GLD16(gA0  + ko, (char*)As[nb] + tid * 16);
          GLD16(gA1  + ko, (char*)As[nb] + 8192 + tid * 16);
          GLD16(gBw0 + ko, (char*)Bs[nb] + tid * 16);
          GLD16(gBw1 + ko, (char*)Bs[nb] + 8192 + tid * 16);
        } else {                                   // stage (w+1, kt=0)
          GLD16(nA0,         (char*)As[nb] + tid * 16);
          GLD16(nA1,         (char*)As[nb] + 8192 + tid * 16);
          GLD16(gBw0 + 1024, (char*)Bs[nb] + tid * 16);
          GLD16(gBw1 + 1024, (char*)Bs[nb] + 8192 + tid * 16);
        }
        asm volatile("s_waitcnt vmcnt(4)" ::: "memory");   // tile t done; t+1 in flight
      } else {
        asm volatile("s_waitcnt vmcnt(0)" ::: "memory");   // final tile
      }
      __builtin_amdgcn_s_barrier();                // all waves have tile t in LDS

      const char* Ab = (const char*)As[cur];
      const char* Bb = (const char*)Bs[cur];
#pragma unroll
      for (int kk = 0; kk < 2; ++kk) {
        s16x8 af[4], bfr[2];
#pragma unroll
        for (int m = 0; m < 4; ++m) {
          int row = wr * 64 + m * 16 + fr;
          af[m] = *(const s16x8*)(Ab + row * 128 + ((kk * 64 + fq * 16) ^ ((row & 7) << 4)));
        }
#pragma unroll
        for (int n = 0; n < 2; ++n) {
          int row = wc * 32 + n * 16 + fr;
          bfr[n] = *(const s16x8*)(Bb + row * 128 + ((kk * 64 + fq * 16) ^ ((row & 7) << 4)));
        }
        asm volatile("s_waitcnt lgkmcnt(0)" ::: "memory");
        __builtin_amdgcn_sched_barrier(0);         // rule #18: pin MFMA after the wait
#pragma unroll
        for (int m = 0; m < 4; ++m)
#pragma unroll
          for (int n = 0; n < 2; ++n)
            acc[m][n] = __builtin_amdgcn_mfma_f32_16x16x32_bf16(af[m], bfr[n], acc[m][n], 0, 0, 0);
      }
      if (kt == 7) {
        // fold: accOut += att[row][w] * acc; acc = 0  (registers + att_s only)
#pragma unroll
        for (int m = 0; m < 4; ++m) {
          float a0 = att_s[(wr * 64 + m * 16 + fq * 4 + 0) * 5 + w];
          float a1 = att_s[(wr * 64 + m * 16 + fq * 4 + 1) * 5 + w];
          float a2 = att_s[(wr * 64 + m * 16 + fq * 4 + 2) * 5 + w];
          float a3 = att_s[(wr * 64 + m * 16 + fq * 4 + 3) * 5 + w];
#pragma unroll
          for (int n = 0; n < 2; ++n) {
            accOut[m][n][0] += a0 * acc[m][n][0];
            accOut[m][n][1] += a1 * acc[m][n][1];
            accOut[m][n][2] += a2 * acc[m][n][2];
            accOut[m][n][3] += a3 * acc[m][n][3];
            acc[m][n] = f32x4{0.f, 0.f, 0.f, 0.f};
          }
        }
      }
      __builtin_amdgcn_s_barrier();                // my ds_reads done -> buf reusable
      cur ^= 1;
    }
    gA0 = nA0;
    gA1 = nA1;
  }

#pragma unroll
  for (int m = 0; m < 4; ++m)
#pragma unroll
    for (int n = 0; n < 2; ++n)
#pragma unroll
      for (int r = 0; r < 4; ++r) {
        int row = brow + wr * 64 + m * 16 + fq * 4 + r;
        int col = bcol + wc * 32 + n * 16 + fr;
        out[(size_t)row * NH + col] = accOut[m][n][r] + cnnb[col];
      }
}

// ---------------- launch ----------------

extern "C" void kernel_launch(void* const* d_in, const int* in_sizes, int n_in,
                              void* d_out, int out_size, void* d_ws, size_t ws_size,
                              hipStream_t stream) {
  const float* X    = (const float*)d_in[0];
  const float* Wq   = (const float*)d_in[1];
  const float* Wk   = (const float*)d_in[2];
  const float* vatt = (const float*)d_in[3];
  const float* cnnW = (const float*)d_in[4];
  const float* cnnb = (const float*)d_in[5];
  float* out = (float*)d_out;

  char* ws = (char*)d_ws;
  u16*   Xb  = (u16*)ws;                            // 32768*512*2  =  33,554,432 B
  u16*   Wt1 = (u16*)(ws + 33554432);               // 1024*512*2   =   1,048,576 B
  u16*   Wt2 = (u16*)(ws + 34603008);               // 512*2560*2   =   2,621,440 B
  u16*   QKb = (u16*)(ws + 37224448);               // 32768*1024*2 =  67,108,864 B
  float* att = (float*)(ws + 104333312);            // 32768*5*4    =     655,360 B
                                                    // total ~105 MB

  cvt_all<<<dim3(XBLOCKS + WBLOCKS), dim3(256), 0, stream>>>(X, Wq, Wk, cnnW, Xb, Wt1, Wt2);
  gemm_qk<<<dim3(2048), dim3(512), 0, stream>>>(Xb, Wt1, QKb);
  scores_att<<<dim3(NROW / 4), dim3(256), 0, stream>>>(QKb, vatt, att);
  gemm_out<<<dim3(1024), dim3(512), 0, stream>>>(Xb, Wt2, att, cnnb, out);
}